// Round 5
// 254.047 us; speedup vs baseline: 1.0467x; 1.0467x over previous
//
#include <hip/hip_runtime.h>

// GADBase guided anisotropic diffusion on MI355X — round 16.
// R14/R15 (poller-wave + LDS halo architecture) both FAILED with absmax ~0.4
// under two different poll implementations -> structural race in that
// architecture; abandoned (no way to localize it headless). R16 returns to
// the VERIFIED R13 kernel (passed, 266us total / 200us persist) and makes one
// surgical change pair aimed at the measured per-round wait (3.1us/round vs
// ~0.9us issue work, VALUBusy 31%):
//  - DELETE the speculative pre-barrier halo loads (they issue concurrently
//    with the neighbor's publish -> nearly always stale -> their vmcnt(0)
//    drain at the barrier + serialized repoll was the wait).
//  - loop barrier becomes raw {s_waitcnt lgkmcnt(0); s_barrier} — LDS
//    visibility only; publish stores cross the barrier in flight.
//  - halos are polled FRESH after the barrier, all four edges issued in
//    parallel per iteration, one vmcnt(0) drain per iteration (same verified
//    uld4/vwait/tags_ok shape as R13's repoll).
// Everything else is byte-identical to R13: 4 waves, TPB 256, shuffle-
// repacked row publishes, tagged full-line uncached publishes, parity-2
// slots, fused conductance/shift/output phases, one barrier per step.

#define BB 2
#define HH 1024
#define WW 1024
#define NPIX (HH * WW)
#define CVN (1023 * 1024)
#define SHW (128 * 128)
#define LL 0.24f
#define KK2 (0.03f * 0.03f)
#define EPSF 1e-8f
#define DEPSF 0.1f
#define NPRE 64
#define NB 512            // 2 blocks/CU on 256 CUs — co-resident
#define TPB 256

typedef unsigned long long u64;
typedef unsigned int uint4v __attribute__((ext_vector_type(4)));
#define ROWPAR ((size_t)NB * 2 * 128)   // u64s per parity plane (row buffers)
#define COLPAR ((size_t)NB * 2 * 32)

// uncached (MALL-coherent) 16B store / load
__device__ inline void ust4(void* p, uint4v q) {
    asm volatile("global_store_dwordx4 %0, %1, off sc0 sc1" :: "v"(p), "v"(q) : "memory");
}
__device__ inline uint4v uld4(const void* p) {
    uint4v r;
    asm volatile("global_load_dwordx4 %0, %1, off sc0 sc1" : "=v"(r) : "v"(p) : "memory");
    return r;
}
__device__ inline void vwait() { asm volatile("s_waitcnt vmcnt(0)" ::: "memory"); }

__device__ inline void pub2(u64* p, float v0, float v1, unsigned s) {
    uint4v q;
    q.x = __float_as_uint(v0); q.y = s;
    q.z = __float_as_uint(v1); q.w = s;
    ust4(p, q);
}
__device__ inline bool tags_ok(uint4v a, uint4v b, unsigned s) {
    return a.y == s && a.w == s && b.y == s && b.w == s;
}
__device__ inline float4 vals_of(uint4v a, uint4v b) {
    return make_float4(__uint_as_float(a.x), __uint_as_float(a.z),
                       __uint_as_float(b.x), __uint_as_float(b.z));
}

__device__ inline float gfun(float d) { return 1.0f / (1.0f + (d * d) / KK2); }

// raw barrier: LDS visibility only (ds ops drain via lgkmcnt). Publish
// stores (vmcnt) deliberately NOT drained — consumed only by other blocks
// via tag polls. sched_barrier(0) pins ordering per rule #18.
#define BAR() do { asm volatile("s_waitcnt lgkmcnt(0)" ::: "memory"); \
                   __builtin_amdgcn_s_barrier();                      \
                   __builtin_amdgcn_sched_barrier(0); } while (0)

__launch_bounds__(TPB, 2)
__global__ void persist_kernel(const float* __restrict__ guide, const float* __restrict__ yb,
                               const float* __restrict__ src, const float* __restrict__ mask,
                               float* __restrict__ out, float* __restrict__ out_cv,
                               float* __restrict__ out_ch,
                               u64* __restrict__ bufRow, u64* __restrict__ bufCol) {
    __shared__ float tile[2][32 * 128];
    __shared__ float sm[4];
    int blk = blockIdx.x;
    int b = blk >> 8;
    int r = blk & 255;
    int tileY = r >> 3;          // 0..31
    int tileX = r & 7;           // 0..7
    int tid = threadIdx.x;
    int cyL = tid >> 5;          // 0..7
    int g = tid & 31;            // 0..31
    int wv = tid >> 6;           // wave 0..3
    int l0 = tid & 63;           // lane within wave
    int lx0 = g * 4;
    int ly0 = cyL * 4;
    int gx = tileX * 128 + lx0;
    int gy = tileY * 32 + ly0;

    // ---- phase 0: shift (redundant per-block, deterministic order) ----
    float mmin = 1e30f;
    const float4* s4 = (const float4*)src;
    for (int i = tid; i < (BB * SHW) / 4; i += TPB) {
        float4 v = s4[i];
        mmin = fminf(mmin, fminf(fminf(v.x, v.y), fminf(v.z, v.w)));
    }
    for (int off = 32; off > 0; off >>= 1) mmin = fminf(mmin, __shfl_down(mmin, off));
    if ((tid & 63) == 0) sm[tid >> 6] = mmin;
    __syncthreads();
    float mm = fminf(fminf(sm[0], sm[1]), fminf(sm[2], sm[3]));
    float shift = (mm <= DEPSF) ? DEPSF : 0.0f;

    // ---- phase 1: conductances from guide/yb (shift cancels in diffs) ----
    int ry[6];
#pragma unroll
    for (int j = 0; j < 6; ++j) {
        int y = gy - 1 + j;
        ry[j] = y < 0 ? 0 : (y > 1023 ? 1023 : y);   // clamped; OOR results forced 0
    }
    int cxl = (gx > 0) ? gx - 1 : 0;
    int cxr = (gx + 4 < 1024) ? gx + 4 : 1023;
    float4 z4 = make_float4(0.f, 0.f, 0.f, 0.f);
    float4 vd[5] = {z4, z4, z4, z4, z4};
    float4 hd[4] = {z4, z4, z4, z4};
    float hmd[4] = {0.f, 0.f, 0.f, 0.f};
    float4 imv[4], r0v = z4, r5v = z4;
    float slv[4], srv[4];
#pragma unroll
    for (int c = 0; c < 4; ++c) {
        const float* F = (c < 3) ? guide + ((size_t)b * 3 + c) * NPIX
                                 : yb + (size_t)b * NPIX;
        float4 rr[6];
#pragma unroll
        for (int j = 0; j < 6; ++j)
            rr[j] = *(const float4*)(F + (size_t)ry[j] * WW + gx);
#pragma unroll
        for (int j = 0; j < 5; ++j) {
            vd[j].x += fabsf(rr[j + 1].x - rr[j].x);
            vd[j].y += fabsf(rr[j + 1].y - rr[j].y);
            vd[j].z += fabsf(rr[j + 1].z - rr[j].z);
            vd[j].w += fabsf(rr[j + 1].w - rr[j].w);
        }
#pragma unroll
        for (int k = 0; k < 4; ++k) {
            float4 R = rr[k + 1];
            float sr = F[(size_t)ry[k + 1] * WW + cxr];
            float sl = F[(size_t)ry[k + 1] * WW + cxl];
            hd[k].x += fabsf(R.y - R.x);
            hd[k].y += fabsf(R.z - R.y);
            hd[k].z += fabsf(R.w - R.z);
            hd[k].w += fabsf(sr - R.w);
            hmd[k] += fabsf(R.x - sl);
            if (c == 3) { imv[k] = R; slv[k] = sl; srv[k] = sr; }
        }
        if (c == 3) { r0v = rr[0]; r5v = rr[5]; }
    }
    float4 cvR[5], chR[4];
    float hmR[4];
#pragma unroll
    for (int j = 0; j < 5; ++j) {
        int y = gy - 1 + j;
        if (y < 0 || y > 1022) {
            cvR[j] = z4;
        } else {
            cvR[j] = make_float4(gfun(vd[j].x * 0.25f), gfun(vd[j].y * 0.25f),
                                 gfun(vd[j].z * 0.25f), gfun(vd[j].w * 0.25f));
        }
    }
#pragma unroll
    for (int k = 0; k < 4; ++k) {
        chR[k] = make_float4(gfun(hd[k].x * 0.25f), gfun(hd[k].y * 0.25f),
                             gfun(hd[k].z * 0.25f), gfun(hd[k].w * 0.25f));
        if (gx + 3 == 1023) chR[k].w = 0.f;      // no conductance past right edge
        hmR[k] = (gx > 0) ? gfun(hmd[k] * 0.25f) : 0.f;
    }
    // cv/ch output slices for this tile
#pragma unroll
    for (int j = 1; j < 5; ++j) {
        int y = gy + j - 1;
        if (y <= 1022)
            *(float4*)(out_cv + (size_t)b * CVN + (size_t)y * WW + gx) = cvR[j];
    }
#pragma unroll
    for (int k = 0; k < 4; ++k) {
        float* base = out_ch + (size_t)b * CVN + (size_t)(gy + k) * 1023;
        base[gx + 0] = chR[k].x;                 // gx+2 <= 1022 always
        base[gx + 1] = chR[k].y;
        base[gx + 2] = chR[k].z;
        if (gx + 3 < 1023) base[gx + 3] = chR[k].w;
    }

    int sidx = b * SHW + (tileY * 4 + (cyL >> 1)) * 128 + tileX * 16 + (g >> 1);
    float sval = src[sidx] + shift;
    bool masked = mask[sidx] < 0.5f;

    bool upAct = (cyL == 0 && tileY > 0);
    bool dnAct = (cyL == 7 && tileY < 31);
    bool lAct  = (g == 0  && tileX > 0);
    bool rAct  = (g == 31 && tileX < 7);
    bool pubTop = (wv == 0 && tileY > 0);
    bool pubBot = (wv == 3 && tileY < 31);

    float* cur = &tile[0][0];
    float* nxt = &tile[1][0];

    // LDS interior (img0 = yb + shift) + state-0 halo registers
#pragma unroll
    for (int k = 0; k < 4; ++k) {
        float4 v = imv[k];
        v.x += shift; v.y += shift; v.z += shift; v.w += shift;
        *(float4*)&cur[(ly0 + k) * 128 + lx0] = v;
    }
    float4 hUp = z4, hDn = z4;
    float xlR[4] = {0.f, 0.f, 0.f, 0.f}, xrR[4] = {0.f, 0.f, 0.f, 0.f};
    if (upAct) { hUp = r0v; hUp.x += shift; hUp.y += shift; hUp.z += shift; hUp.w += shift; }
    if (dnAct) { hDn = r5v; hDn.x += shift; hDn.y += shift; hDn.z += shift; hDn.w += shift; }
    if (lAct) {
#pragma unroll
        for (int k = 0; k < 4; ++k) xlR[k] = slv[k] + shift;
    }
    if (rAct) {
#pragma unroll
        for (int k = 0; k < 4; ++k) xrR[k] = srv[k] + shift;
    }
    __syncthreads();

    float4 nv[4];
    for (int t = 0; t < NPRE; ++t) {
        // ---- A: diffuse + adjust, state t -> nv = state t+1 ----
        float4 rUp = (cyL == 0) ? hUp : *(float4*)&cur[(ly0 - 1) * 128 + lx0];
        float4 rC  = *(float4*)&cur[ly0 * 128 + lx0];
        float csum = 0.f;
#pragma unroll
        for (int k = 0; k < 4; ++k) {
            float4 rDn = (k == 3 && cyL == 7) ? hDn
                       : *(float4*)&cur[(ly0 + 1 + k) * 128 + lx0];
            float4 cu = cvR[k], cd = cvR[k + 1], h4 = chR[k];
            float xl = __shfl_up(rC.w, 1);
            float xr = __shfl_down(rC.x, 1);
            float hm = hmR[k];
            if (g == 0)  xl = xlR[k];
            if (g == 31) xr = xrR[k];
            float4 a;
            a.x = rC.x + LL * (cd.x * (rDn.x - rC.x) - cu.x * (rC.x - rUp.x)
                             + h4.x * (rC.y - rC.x) - hm   * (rC.x - xl));
            a.y = rC.y + LL * (cd.y * (rDn.y - rC.y) - cu.y * (rC.y - rUp.y)
                             + h4.y * (rC.z - rC.y) - h4.x * (rC.y - rC.x));
            a.z = rC.z + LL * (cd.z * (rDn.z - rC.z) - cu.z * (rC.z - rUp.z)
                             + h4.z * (rC.w - rC.z) - h4.y * (rC.z - rC.y));
            a.w = rC.w + LL * (cd.w * (rDn.w - rC.w) - cu.w * (rC.w - rUp.w)
                             + h4.w * (xr   - rC.w) - h4.z * (rC.w - rC.z));
            nv[k] = a;
            csum += a.x + a.y + a.z + a.w;
            rUp = rC; rC = rDn;
        }
        csum += __shfl_xor(csum, 1);
        csum += __shfl_xor(csum, 32);   // 8x8 cell = lanes {tid,tid^1,tid^32,tid^33}
        float ratio = masked ? 1.0f : sval / (csum * (1.0f / 64.0f) + EPSF);

        if (t == NPRE - 1) {
            float* ob = out + (size_t)b * NPIX;
#pragma unroll
            for (int k = 0; k < 4; ++k) {
                float4 v = nv[k];
                v.x = v.x * ratio - shift; v.y = v.y * ratio - shift;
                v.z = v.z * ratio - shift; v.w = v.w * ratio - shift;
                *(float4*)(ob + (size_t)(gy + k) * WW + gx) = v;
            }
            break;
        }
#pragma unroll
        for (int k = 0; k < 4; ++k) {
            nv[k].x *= ratio; nv[k].y *= ratio; nv[k].z *= ratio; nv[k].w *= ratio;
        }

        // ---- B: publish edges tagged s2; rows = one wave-wide dwordx4 ----
        unsigned s2 = (unsigned)(t + 1);
        size_t rOff2 = (s2 & 1) ? ROWPAR : 0;
        size_t cOff2 = (s2 & 1) ? COLPAR : 0;
        if (pubTop) {   // wave 0: top row (values live in lanes 0..31 = cyL 0)
            float a = __shfl(nv[0].x, l0 >> 1), bq = __shfl(nv[0].y, l0 >> 1);
            float c = __shfl(nv[0].z, l0 >> 1), d = __shfl(nv[0].w, l0 >> 1);
            float v0 = (l0 & 1) ? c : a, v1 = (l0 & 1) ? d : bq;
            uint4v q; q.x = __float_as_uint(v0); q.y = s2;
            q.z = __float_as_uint(v1); q.w = s2;
            ust4(&bufRow[rOff2 + ((size_t)blk * 2 + 0) * 128 + 2 * l0], q);
        }
        if (pubBot) {   // wave 3: bottom row (values in local lanes 32..63 = cyL 7)
            int sl = 32 + (l0 >> 1);
            float a = __shfl(nv[3].x, sl), bq = __shfl(nv[3].y, sl);
            float c = __shfl(nv[3].z, sl), d = __shfl(nv[3].w, sl);
            float v0 = (l0 & 1) ? c : a, v1 = (l0 & 1) ? d : bq;
            uint4v q; q.x = __float_as_uint(v0); q.y = s2;
            q.z = __float_as_uint(v1); q.w = s2;
            ust4(&bufRow[rOff2 + ((size_t)blk * 2 + 1) * 128 + 2 * l0], q);
        }
        if (lAct) {     // 64B line per wave
            u64* p = &bufCol[cOff2 + ((size_t)blk * 2 + 0) * 32 + ly0];
            pub2(p, nv[0].x, nv[1].x, s2);
            pub2(p + 2, nv[2].x, nv[3].x, s2);
        }
        if (rAct) {
            u64* p = &bufCol[cOff2 + ((size_t)blk * 2 + 1) * 32 + ly0];
            pub2(p, nv[0].w, nv[1].w, s2);
            pub2(p + 2, nv[2].w, nv[3].w, s2);
        }

        // ---- C: interior of state t+1 into nxt; raw barrier (lgkm only) ----
#pragma unroll
        for (int k = 0; k < 4; ++k)
            *(float4*)&nxt[(ly0 + k) * 128 + lx0] = nv[k];
        BAR();   // publish stores cross in flight; LDS visible

        // ---- D: poll halos fresh; all edges in parallel, one drain/iter ----
        const u64* pUp = upAct ? &bufRow[rOff2 + (((size_t)blk - 8) * 2 + 1) * 128 + lx0] : nullptr;
        const u64* pDn = dnAct ? &bufRow[rOff2 + (((size_t)blk + 8) * 2 + 0) * 128 + lx0] : nullptr;
        const u64* pL  = lAct  ? &bufCol[cOff2 + (((size_t)blk - 1) * 2 + 1) * 32 + ly0] : nullptr;
        const u64* pR  = rAct  ? &bufCol[cOff2 + (((size_t)blk + 1) * 2 + 0) * 32 + ly0] : nullptr;
        bool needU = upAct, needD = dnAct, needL = lAct, needR = rAct;
        uint4v uA, uB, dA, dB, lA, lB, rA, rB;
        for (;;) {
            if (needU) { uA = uld4(pUp); uB = uld4(pUp + 2); }
            if (needD) { dA = uld4(pDn); dB = uld4(pDn + 2); }
            if (needL) { lA = uld4(pL);  lB = uld4(pL + 2); }
            if (needR) { rA = uld4(pR);  rB = uld4(pR + 2); }
            vwait();
            if (needU && tags_ok(uA, uB, s2)) { hUp = vals_of(uA, uB); needU = false; }
            if (needD && tags_ok(dA, dB, s2)) { hDn = vals_of(dA, dB); needD = false; }
            if (needL && tags_ok(lA, lB, s2)) {
                float4 c = vals_of(lA, lB);
                xlR[0] = c.x; xlR[1] = c.y; xlR[2] = c.z; xlR[3] = c.w;
                needL = false;
            }
            if (needR && tags_ok(rA, rB, s2)) {
                float4 c = vals_of(rA, rB);
                xrR[0] = c.x; xrR[1] = c.y; xrR[2] = c.z; xrR[3] = c.w;
                needR = false;
            }
            if (__all(!(needU || needD || needL || needR))) break;
            __builtin_amdgcn_s_sleep(1);
        }
        float* tmp = cur; cur = nxt; nxt = tmp;
    }
}

extern "C" void kernel_launch(void* const* d_in, const int* in_sizes, int n_in,
                              void* d_out, int out_size, void* d_ws, size_t ws_size,
                              hipStream_t stream) {
    const float* guide = (const float*)d_in[0];   // [2,3,1024,1024]
    const float* yb    = (const float*)d_in[1];   // [2,1,1024,1024]
    const float* src   = (const float*)d_in[2];   // [2,1,128,128]
    const float* mask  = (const float*)d_in[3];   // [2,1,128,128]

    float* out    = (float*)d_out;                       // y_pred [2,1,1024,1024]
    float* out_cv = out + (size_t)BB * NPIX;             // cv [2,1,1023,1024]
    float* out_ch = out_cv + (size_t)BB * CVN;           // ch [2,1,1024,1023]

    // ws: only the halo exchange buffers. 0xAA poison cannot match any tag
    // in [1,64), so no zero-init pass is needed.
    u64* bufRow = (u64*)d_ws;                            // 2 par x 512 x 2 x 128
    u64* bufCol = bufRow + 2 * ROWPAR;                   // 2 par x 512 x 2 x 32

    persist_kernel<<<NB, TPB, 0, stream>>>(guide, yb, src, mask, out, out_cv,
                                           out_ch, bufRow, bufCol);
}

// Round 6
// 231.561 us; speedup vs baseline: 1.1484x; 1.0971x over previous
//
#include <hip/hip_runtime.h>

// GADBase guided anisotropic diffusion on MI355X — round 17.
// R16 (PASSED, 254us total / 185us persist): killing the speculative-load
// vmcnt drain + raw lgkm-only barrier bought only 15us -> the dominant wait
// is the serial post-barrier detect chain (poll -> stale -> sleep -> RTT),
// ~1.5-2us of the 2.9us round.
// R17: overlap detect with compute via the LINEAR-CORRECTION split.
// Halo terms enter the update linearly (-cu*(rC-rUp) = -cu*rC + cu*rUp; csum
// likewise), so each round:
//   1. issue the 4 edge poll loads (tag=t) right after the barrier;
//   2. BASE compute for all pixels with halo contributions = 0 (physical
//      borders already have zero conductances -> no special cases);
//   3. vwait + tag-check (loads and the neighbor's store have had the whole
//      base compute to land -> first check nearly always hits; repoll loop
//      kept for skew robustness);
//   4. corrections: edge lanes add LL*cu.hUp / LL*cd.hDn / LL*hm*xl /
//      LL*ch.w*xr to nv AND csum, then shuffles -> ratio -> scale ->
//      publish(t+1) -> LDS write -> barrier.
// Protocol (tags, parity-2 slots, uncached publishes, 0xAA poison) is
// unchanged from R13/R16; the poll is the same verified uld4/vwait/tags_ok
// shape. Only FP rounding order changes (split halo terms).

#define BB 2
#define HH 1024
#define WW 1024
#define NPIX (HH * WW)
#define CVN (1023 * 1024)
#define SHW (128 * 128)
#define LL 0.24f
#define KK2 (0.03f * 0.03f)
#define EPSF 1e-8f
#define DEPSF 0.1f
#define NPRE 64
#define NB 512            // 2 blocks/CU on 256 CUs — co-resident
#define TPB 256

typedef unsigned long long u64;
typedef unsigned int uint4v __attribute__((ext_vector_type(4)));
#define ROWPAR ((size_t)NB * 2 * 128)   // u64s per parity plane (row buffers)
#define COLPAR ((size_t)NB * 2 * 32)

// uncached (MALL-coherent) 16B store / load
__device__ inline void ust4(void* p, uint4v q) {
    asm volatile("global_store_dwordx4 %0, %1, off sc0 sc1" :: "v"(p), "v"(q) : "memory");
}
__device__ inline uint4v uld4(const void* p) {
    uint4v r;
    asm volatile("global_load_dwordx4 %0, %1, off sc0 sc1" : "=v"(r) : "v"(p) : "memory");
    return r;
}
__device__ inline void vwait() { asm volatile("s_waitcnt vmcnt(0)" ::: "memory"); }

__device__ inline void pub2(u64* p, float v0, float v1, unsigned s) {
    uint4v q;
    q.x = __float_as_uint(v0); q.y = s;
    q.z = __float_as_uint(v1); q.w = s;
    ust4(p, q);
}
__device__ inline bool tags_ok(uint4v a, uint4v b, unsigned s) {
    return a.y == s && a.w == s && b.y == s && b.w == s;
}
__device__ inline float4 vals_of(uint4v a, uint4v b) {
    return make_float4(__uint_as_float(a.x), __uint_as_float(a.z),
                       __uint_as_float(b.x), __uint_as_float(b.z));
}

__device__ inline float gfun(float d) { return 1.0f / (1.0f + (d * d) / KK2); }

// raw barrier: LDS visibility only (ds ops drain via lgkmcnt). Publish
// stores (vmcnt) deliberately NOT drained — consumed only by other blocks
// via tag polls. sched_barrier(0) pins ordering per rule #18.
#define BAR() do { asm volatile("s_waitcnt lgkmcnt(0)" ::: "memory"); \
                   __builtin_amdgcn_s_barrier();                      \
                   __builtin_amdgcn_sched_barrier(0); } while (0)

__launch_bounds__(TPB, 2)
__global__ void persist_kernel(const float* __restrict__ guide, const float* __restrict__ yb,
                               const float* __restrict__ src, const float* __restrict__ mask,
                               float* __restrict__ out, float* __restrict__ out_cv,
                               float* __restrict__ out_ch,
                               u64* __restrict__ bufRow, u64* __restrict__ bufCol) {
    __shared__ float tile[2][32 * 128];
    __shared__ float sm[4];
    int blk = blockIdx.x;
    int b = blk >> 8;
    int r = blk & 255;
    int tileY = r >> 3;          // 0..31
    int tileX = r & 7;           // 0..7
    int tid = threadIdx.x;
    int cyL = tid >> 5;          // 0..7
    int g = tid & 31;            // 0..31
    int wv = tid >> 6;           // wave 0..3
    int l0 = tid & 63;           // lane within wave
    int lx0 = g * 4;
    int ly0 = cyL * 4;
    int gx = tileX * 128 + lx0;
    int gy = tileY * 32 + ly0;

    // ---- phase 0: shift (redundant per-block, deterministic order) ----
    float mmin = 1e30f;
    const float4* s4 = (const float4*)src;
    for (int i = tid; i < (BB * SHW) / 4; i += TPB) {
        float4 v = s4[i];
        mmin = fminf(mmin, fminf(fminf(v.x, v.y), fminf(v.z, v.w)));
    }
    for (int off = 32; off > 0; off >>= 1) mmin = fminf(mmin, __shfl_down(mmin, off));
    if ((tid & 63) == 0) sm[tid >> 6] = mmin;
    __syncthreads();
    float mm = fminf(fminf(sm[0], sm[1]), fminf(sm[2], sm[3]));
    float shift = (mm <= DEPSF) ? DEPSF : 0.0f;

    // ---- phase 1: conductances from guide/yb (shift cancels in diffs) ----
    int ry[6];
#pragma unroll
    for (int j = 0; j < 6; ++j) {
        int y = gy - 1 + j;
        ry[j] = y < 0 ? 0 : (y > 1023 ? 1023 : y);   // clamped; OOR results forced 0
    }
    int cxl = (gx > 0) ? gx - 1 : 0;
    int cxr = (gx + 4 < 1024) ? gx + 4 : 1023;
    float4 z4 = make_float4(0.f, 0.f, 0.f, 0.f);
    float4 vd[5] = {z4, z4, z4, z4, z4};
    float4 hd[4] = {z4, z4, z4, z4};
    float hmd[4] = {0.f, 0.f, 0.f, 0.f};
    float4 imv[4], r0v = z4, r5v = z4;
    float slv[4], srv[4];
#pragma unroll
    for (int c = 0; c < 4; ++c) {
        const float* F = (c < 3) ? guide + ((size_t)b * 3 + c) * NPIX
                                 : yb + (size_t)b * NPIX;
        float4 rr[6];
#pragma unroll
        for (int j = 0; j < 6; ++j)
            rr[j] = *(const float4*)(F + (size_t)ry[j] * WW + gx);
#pragma unroll
        for (int j = 0; j < 5; ++j) {
            vd[j].x += fabsf(rr[j + 1].x - rr[j].x);
            vd[j].y += fabsf(rr[j + 1].y - rr[j].y);
            vd[j].z += fabsf(rr[j + 1].z - rr[j].z);
            vd[j].w += fabsf(rr[j + 1].w - rr[j].w);
        }
#pragma unroll
        for (int k = 0; k < 4; ++k) {
            float4 R = rr[k + 1];
            float sr = F[(size_t)ry[k + 1] * WW + cxr];
            float sl = F[(size_t)ry[k + 1] * WW + cxl];
            hd[k].x += fabsf(R.y - R.x);
            hd[k].y += fabsf(R.z - R.y);
            hd[k].z += fabsf(R.w - R.z);
            hd[k].w += fabsf(sr - R.w);
            hmd[k] += fabsf(R.x - sl);
            if (c == 3) { imv[k] = R; slv[k] = sl; srv[k] = sr; }
        }
        if (c == 3) { r0v = rr[0]; r5v = rr[5]; }
    }
    float4 cvR[5], chR[4];
    float hmR[4];
#pragma unroll
    for (int j = 0; j < 5; ++j) {
        int y = gy - 1 + j;
        if (y < 0 || y > 1022) {
            cvR[j] = z4;
        } else {
            cvR[j] = make_float4(gfun(vd[j].x * 0.25f), gfun(vd[j].y * 0.25f),
                                 gfun(vd[j].z * 0.25f), gfun(vd[j].w * 0.25f));
        }
    }
#pragma unroll
    for (int k = 0; k < 4; ++k) {
        chR[k] = make_float4(gfun(hd[k].x * 0.25f), gfun(hd[k].y * 0.25f),
                             gfun(hd[k].z * 0.25f), gfun(hd[k].w * 0.25f));
        if (gx + 3 == 1023) chR[k].w = 0.f;      // no conductance past right edge
        hmR[k] = (gx > 0) ? gfun(hmd[k] * 0.25f) : 0.f;
    }
    // cv/ch output slices for this tile
#pragma unroll
    for (int j = 1; j < 5; ++j) {
        int y = gy + j - 1;
        if (y <= 1022)
            *(float4*)(out_cv + (size_t)b * CVN + (size_t)y * WW + gx) = cvR[j];
    }
#pragma unroll
    for (int k = 0; k < 4; ++k) {
        float* base = out_ch + (size_t)b * CVN + (size_t)(gy + k) * 1023;
        base[gx + 0] = chR[k].x;                 // gx+2 <= 1022 always
        base[gx + 1] = chR[k].y;
        base[gx + 2] = chR[k].z;
        if (gx + 3 < 1023) base[gx + 3] = chR[k].w;
    }

    int sidx = b * SHW + (tileY * 4 + (cyL >> 1)) * 128 + tileX * 16 + (g >> 1);
    float sval = src[sidx] + shift;
    bool masked = mask[sidx] < 0.5f;

    bool upAct = (cyL == 0 && tileY > 0);
    bool dnAct = (cyL == 7 && tileY < 31);
    bool lAct  = (g == 0  && tileX > 0);
    bool rAct  = (g == 31 && tileX < 7);
    bool pubTop = (wv == 0 && tileY > 0);
    bool pubBot = (wv == 3 && tileY < 31);

    float* cur = &tile[0][0];
    float* nxt = &tile[1][0];

    // LDS interior (img0 = yb + shift) + state-0 halo registers
#pragma unroll
    for (int k = 0; k < 4; ++k) {
        float4 v = imv[k];
        v.x += shift; v.y += shift; v.z += shift; v.w += shift;
        *(float4*)&cur[(ly0 + k) * 128 + lx0] = v;
    }
    float4 hUp = z4, hDn = z4;
    float xlR[4] = {0.f, 0.f, 0.f, 0.f}, xrR[4] = {0.f, 0.f, 0.f, 0.f};
    if (upAct) { hUp = r0v; hUp.x += shift; hUp.y += shift; hUp.z += shift; hUp.w += shift; }
    if (dnAct) { hDn = r5v; hDn.x += shift; hDn.y += shift; hDn.z += shift; hDn.w += shift; }
    if (lAct) {
#pragma unroll
        for (int k = 0; k < 4; ++k) xlR[k] = slv[k] + shift;
    }
    if (rAct) {
#pragma unroll
        for (int k = 0; k < 4; ++k) xrR[k] = srv[k] + shift;
    }
    __syncthreads();

    float4 nv[4];
    for (int t = 0; t < NPRE; ++t) {
        // ---- 1: issue poll loads for state-t halos (published by neighbors
        //         at the end of their round t-1; tag = t, parity = t&1) ----
        unsigned sP = (unsigned)t;
        size_t rOffP = (t & 1) ? ROWPAR : 0;
        size_t cOffP = (t & 1) ? COLPAR : 0;
        const u64* pUp = upAct ? &bufRow[rOffP + (((size_t)blk - 8) * 2 + 1) * 128 + lx0] : nullptr;
        const u64* pDn = dnAct ? &bufRow[rOffP + (((size_t)blk + 8) * 2 + 0) * 128 + lx0] : nullptr;
        const u64* pL  = lAct  ? &bufCol[cOffP + (((size_t)blk - 1) * 2 + 1) * 32 + ly0] : nullptr;
        const u64* pR  = rAct  ? &bufCol[cOffP + (((size_t)blk + 1) * 2 + 0) * 32 + ly0] : nullptr;
        uint4v uA, uB, dA, dB, lA, lB, rA, rB;
        bool pollRound = (t > 0);    // t==0 halos live in registers from init
        if (pollRound) {
            if (upAct) { uA = uld4(pUp); uB = uld4(pUp + 2); }
            if (dnAct) { dA = uld4(pDn); dB = uld4(pDn + 2); }
            if (lAct)  { lA = uld4(pL);  lB = uld4(pL + 2); }
            if (rAct)  { rA = uld4(pR);  rB = uld4(pR + 2); }
        }

        // ---- 2: BASE diffuse, halo contributions = 0 (borders have zero
        //         conductance so no special cases needed) ----
        float4 rUp = (cyL == 0) ? z4 : *(float4*)&cur[(ly0 - 1) * 128 + lx0];
        float4 rC  = *(float4*)&cur[ly0 * 128 + lx0];
        float csum = 0.f;
#pragma unroll
        for (int k = 0; k < 4; ++k) {
            float4 rDn = (k == 3 && cyL == 7) ? z4
                       : *(float4*)&cur[(ly0 + 1 + k) * 128 + lx0];
            float4 cu = cvR[k], cd = cvR[k + 1], h4 = chR[k];
            float xs = __shfl_up(rC.w, 1);
            float xt = __shfl_down(rC.x, 1);
            float xl = (g == 0)  ? 0.f : xs;
            float xr = (g == 31) ? 0.f : xt;
            float hm = hmR[k];
            float4 a;
            a.x = rC.x + LL * (cd.x * (rDn.x - rC.x) - cu.x * (rC.x - rUp.x)
                             + h4.x * (rC.y - rC.x) - hm   * (rC.x - xl));
            a.y = rC.y + LL * (cd.y * (rDn.y - rC.y) - cu.y * (rC.y - rUp.y)
                             + h4.y * (rC.z - rC.y) - h4.x * (rC.y - rC.x));
            a.z = rC.z + LL * (cd.z * (rDn.z - rC.z) - cu.z * (rC.z - rUp.z)
                             + h4.z * (rC.w - rC.z) - h4.y * (rC.z - rC.y));
            a.w = rC.w + LL * (cd.w * (rDn.w - rC.w) - cu.w * (rC.w - rUp.w)
                             + h4.w * (xr   - rC.w) - h4.z * (rC.w - rC.z));
            nv[k] = a;
            csum += a.x + a.y + a.z + a.w;
            rUp = rC; rC = rDn;
        }

        // ---- 3: resolve halos (loads have had the base compute to land) ----
        if (pollRound) {
            vwait();
            bool needU = upAct, needD = dnAct, needL = lAct, needR = rAct;
            for (;;) {
                if (needU && tags_ok(uA, uB, sP)) { hUp = vals_of(uA, uB); needU = false; }
                if (needD && tags_ok(dA, dB, sP)) { hDn = vals_of(dA, dB); needD = false; }
                if (needL && tags_ok(lA, lB, sP)) {
                    float4 c = vals_of(lA, lB);
                    xlR[0] = c.x; xlR[1] = c.y; xlR[2] = c.z; xlR[3] = c.w;
                    needL = false;
                }
                if (needR && tags_ok(rA, rB, sP)) {
                    float4 c = vals_of(rA, rB);
                    xrR[0] = c.x; xrR[1] = c.y; xrR[2] = c.z; xrR[3] = c.w;
                    needR = false;
                }
                if (__all(!(needU || needD || needL || needR))) break;
                __builtin_amdgcn_s_sleep(1);
                if (needU) { uA = uld4(pUp); uB = uld4(pUp + 2); }
                if (needD) { dA = uld4(pDn); dB = uld4(pDn + 2); }
                if (needL) { lA = uld4(pL);  lB = uld4(pL + 2); }
                if (needR) { rA = uld4(pR);  rB = uld4(pR + 2); }
                vwait();
            }
        }

        // ---- 4: linear corrections (zero-conductance borders self-mask) ----
        float cadd = 0.f;
        if (cyL == 0) {
            float4 cu = cvR[0];
            float c0 = LL * cu.x * hUp.x, c1 = LL * cu.y * hUp.y;
            float c2 = LL * cu.z * hUp.z, c3 = LL * cu.w * hUp.w;
            nv[0].x += c0; nv[0].y += c1; nv[0].z += c2; nv[0].w += c3;
            cadd += c0 + c1 + c2 + c3;
        }
        if (cyL == 7) {
            float4 cd = cvR[4];
            float c0 = LL * cd.x * hDn.x, c1 = LL * cd.y * hDn.y;
            float c2 = LL * cd.z * hDn.z, c3 = LL * cd.w * hDn.w;
            nv[3].x += c0; nv[3].y += c1; nv[3].z += c2; nv[3].w += c3;
            cadd += c0 + c1 + c2 + c3;
        }
        if (g == 0) {
#pragma unroll
            for (int k = 0; k < 4; ++k) {
                float c = LL * hmR[k] * xlR[k];
                nv[k].x += c; cadd += c;
            }
        }
        if (g == 31) {
#pragma unroll
            for (int k = 0; k < 4; ++k) {
                float c = LL * chR[k].w * xrR[k];
                nv[k].w += c; cadd += c;
            }
        }
        csum += cadd;

        csum += __shfl_xor(csum, 1);
        csum += __shfl_xor(csum, 32);   // 8x8 cell = lanes {tid,tid^1,tid^32,tid^33}
        float ratio = masked ? 1.0f : sval / (csum * (1.0f / 64.0f) + EPSF);

        if (t == NPRE - 1) {
            float* ob = out + (size_t)b * NPIX;
#pragma unroll
            for (int k = 0; k < 4; ++k) {
                float4 v = nv[k];
                v.x = v.x * ratio - shift; v.y = v.y * ratio - shift;
                v.z = v.z * ratio - shift; v.w = v.w * ratio - shift;
                *(float4*)(ob + (size_t)(gy + k) * WW + gx) = v;
            }
            break;
        }
#pragma unroll
        for (int k = 0; k < 4; ++k) {
            nv[k].x *= ratio; nv[k].y *= ratio; nv[k].z *= ratio; nv[k].w *= ratio;
        }

        // ---- 5: publish edges tagged s2 = t+1; rows = wave-wide dwordx4 ----
        unsigned s2 = (unsigned)(t + 1);
        size_t rOff2 = (s2 & 1) ? ROWPAR : 0;
        size_t cOff2 = (s2 & 1) ? COLPAR : 0;
        if (pubTop) {   // wave 0: top row (values live in lanes 0..31 = cyL 0)
            float a = __shfl(nv[0].x, l0 >> 1), bq = __shfl(nv[0].y, l0 >> 1);
            float c = __shfl(nv[0].z, l0 >> 1), d = __shfl(nv[0].w, l0 >> 1);
            float v0 = (l0 & 1) ? c : a, v1 = (l0 & 1) ? d : bq;
            uint4v q; q.x = __float_as_uint(v0); q.y = s2;
            q.z = __float_as_uint(v1); q.w = s2;
            ust4(&bufRow[rOff2 + ((size_t)blk * 2 + 0) * 128 + 2 * l0], q);
        }
        if (pubBot) {   // wave 3: bottom row (values in local lanes 32..63 = cyL 7)
            int sl = 32 + (l0 >> 1);
            float a = __shfl(nv[3].x, sl), bq = __shfl(nv[3].y, sl);
            float c = __shfl(nv[3].z, sl), d = __shfl(nv[3].w, sl);
            float v0 = (l0 & 1) ? c : a, v1 = (l0 & 1) ? d : bq;
            uint4v q; q.x = __float_as_uint(v0); q.y = s2;
            q.z = __float_as_uint(v1); q.w = s2;
            ust4(&bufRow[rOff2 + ((size_t)blk * 2 + 1) * 128 + 2 * l0], q);
        }
        if (lAct) {     // 64B line per wave
            u64* p = &bufCol[cOff2 + ((size_t)blk * 2 + 0) * 32 + ly0];
            pub2(p, nv[0].x, nv[1].x, s2);
            pub2(p + 2, nv[2].x, nv[3].x, s2);
        }
        if (rAct) {
            u64* p = &bufCol[cOff2 + ((size_t)blk * 2 + 1) * 32 + ly0];
            pub2(p, nv[0].w, nv[1].w, s2);
            pub2(p + 2, nv[2].w, nv[3].w, s2);
        }

        // ---- 6: interior of state t+1 into nxt; raw barrier (lgkm only) ----
#pragma unroll
        for (int k = 0; k < 4; ++k)
            *(float4*)&nxt[(ly0 + k) * 128 + lx0] = nv[k];
        BAR();   // publish stores cross in flight; LDS visible
        float* tmp = cur; cur = nxt; nxt = tmp;
    }
}

extern "C" void kernel_launch(void* const* d_in, const int* in_sizes, int n_in,
                              void* d_out, int out_size, void* d_ws, size_t ws_size,
                              hipStream_t stream) {
    const float* guide = (const float*)d_in[0];   // [2,3,1024,1024]
    const float* yb    = (const float*)d_in[1];   // [2,1,1024,1024]
    const float* src   = (const float*)d_in[2];   // [2,1,128,128]
    const float* mask  = (const float*)d_in[3];   // [2,1,128,128]

    float* out    = (float*)d_out;                       // y_pred [2,1,1024,1024]
    float* out_cv = out + (size_t)BB * NPIX;             // cv [2,1,1023,1024]
    float* out_ch = out_cv + (size_t)BB * CVN;           // ch [2,1,1024,1023]

    // ws: only the halo exchange buffers. 0xAA poison cannot match any tag
    // in [1,64), so no zero-init pass is needed.
    u64* bufRow = (u64*)d_ws;                            // 2 par x 512 x 2 x 128
    u64* bufCol = bufRow + 2 * ROWPAR;                   // 2 par x 512 x 2 x 32

    persist_kernel<<<NB, TPB, 0, stream>>>(guide, yb, src, mask, out, out_cv,
                                           out_ch, bufRow, bufCol);
}